// Round 5
// baseline (97.439 us; speedup 1.0000x reference)
//
#include <hip/hip_runtime.h>

#define B_ 8
#define T_ 2048
#define C_ 768
#define H_ 64
#define QT_ (T_ / 64)   // 32 Q-tiles
#define CH_ 8           // j-tiles per chunk
#define NCH_ 4          // max chunks per Q-tile

typedef __bf16 bf16x8 __attribute__((ext_vector_type(8)));
typedef unsigned short ushort8 __attribute__((ext_vector_type(8)));
typedef float f32x4 __attribute__((ext_vector_type(4)));

typedef __attribute__((address_space(1))) const void g_void;
typedef __attribute__((address_space(3))) void lds_void;

static __device__ __forceinline__ unsigned short f32_to_bf16(float f) {
  unsigned int u = __float_as_uint(f);
  u += 0x7FFFu + ((u >> 16) & 1u);
  return (unsigned short)(u >> 16);
}

static __device__ __forceinline__ unsigned int cvtpk_bf16(float a, float b) {
  unsigned int r;
  asm("v_cvt_pk_bf16_f32 %0, %1, %2" : "=v"(r) : "v"(a), "v"(b));
  return r;
}

static __device__ __forceinline__ f32x4 mfma16(ushort8 a, ushort8 b, f32x4 c) {
  return __builtin_amdgcn_mfma_f32_16x16x32_bf16(
      __builtin_bit_cast(bf16x8, a), __builtin_bit_cast(bf16x8, b), c, 0, 0, 0);
}

// ---------------- Kernel 0: W -> Wt in PRE-SWIZZLED per-K-step tiled layout ----------
__global__ void prep_w_kernel(const float* __restrict__ Wk, const float* __restrict__ Wq,
                              const float* __restrict__ Wv, unsigned short* __restrict__ Wt) {
  int g = blockIdx.x * 256 + threadIdx.x;
  if (g >= 24 * 768) return;
  int ks = g / 768, s = g - ks * 768;
  int n = s >> 2, perm = s & 3;
  int k8 = perm ^ (n & 3) ^ ((n >> 2) & 3);
  int p = n >> 6, col = n & 63;
  const float* W = (p == 0) ? Wk : (p == 1) ? Wq : Wv;
  float sc = (p == 1) ? 0.125f * 1.44269504088896f : 1.0f;
  int kbase = ks * 32 + k8 * 8;
  ushort8 v;
#pragma unroll
  for (int e = 0; e < 8; ++e) v[e] = f32_to_bf16(W[(kbase + e) * 64 + col] * sc);
  *(ushort8*)(Wt + (size_t)g * 8) = v;
}

// ---------------- Kernel 1: projections as LDS-staged pipelined GEMM -----------------
__global__ __launch_bounds__(256) void proj_kernel(
    const float* __restrict__ x, const unsigned short* __restrict__ Wt,
    unsigned short* __restrict__ Qb, unsigned short* __restrict__ Kb,
    unsigned short* __restrict__ Vt) {
  __shared__ unsigned short Wl[2][6144];
  __shared__ unsigned short Xl[2][1024];
  const int tid = threadIdx.x;
  const int wave = tid >> 6, lane = tid & 63;
  const int lo = lane & 15, hi = lane >> 4;
  const int rg = wave & 1, ch2 = wave >> 1;
  const int row0 = blockIdx.x * 32;

  f32x4 acc[6];
#pragma unroll
  for (int t = 0; t < 6; ++t) acc[t] = (f32x4){0.f, 0.f, 0.f, 0.f};

  const int xr = (tid & 127) >> 2;
  const int xk8 = tid & 3;
  const int xslot = xr * 4 + (xk8 ^ (xr & 3) ^ ((xr >> 2) & 3));
  const float* xsrc = x + (size_t)(row0 + xr) * C_ + xk8 * 8;

  const int arow = rg * 16 + lo;
  const int aaddr = (arow * 4 + (hi ^ (arow & 3) ^ ((arow >> 2) & 3))) * 8;

  auto wstage = [&](int buf, int ks) {
    const unsigned short* src = Wt + (size_t)ks * 6144 + tid * 8;
#pragma unroll
    for (int is = 0; is < 3; ++is)
      __builtin_amdgcn_global_load_lds((g_void*)(src + is * 2048),
          (lds_void*)(&Wl[buf][is * 2048 + wave * 512]), 16, 0, 0);
  };

  float4 xa0 = {}, xa1 = {}, xb0 = {}, xb1 = {};

  wstage(0, 0);
  if (tid < 128) {
    xa0 = *(const float4*)(xsrc);
    xa1 = *(const float4*)(xsrc + 4);
  }

  for (int ks = 0; ks < 24; ++ks) {
    const int cur = ks & 1;
    asm volatile("s_waitcnt vmcnt(0)" ::: "memory");
    __syncthreads();
    if (ks + 1 < 24) {
      wstage(cur ^ 1, ks + 1);
      if (tid < 128) {
        xb0 = *(const float4*)(xsrc + (ks + 1) * 32);
        xb1 = *(const float4*)(xsrc + (ks + 1) * 32 + 4);
      }
    }
    if (tid < 128) {
      unsigned int dd[4];
      dd[0] = cvtpk_bf16(xa0.x, xa0.y);
      dd[1] = cvtpk_bf16(xa0.z, xa0.w);
      dd[2] = cvtpk_bf16(xa1.x, xa1.y);
      dd[3] = cvtpk_bf16(xa1.z, xa1.w);
      *(uint4*)(&Xl[cur][xslot * 8]) = *(uint4*)dd;
    }
    __syncthreads();
    ushort8 af = *(const ushort8*)(&Xl[cur][aaddr]);
#pragma unroll
    for (int t = 0; t < 6; ++t) {
      const int n = ch2 * 96 + t * 16 + lo;
      const int baddr = (n * 4 + (hi ^ (n & 3) ^ ((n >> 2) & 3))) * 8;
      ushort8 bfr = *(const ushort8*)(&Wl[cur][baddr]);
      acc[t] = mfma16(af, bfr, acc[t]);
    }
    xa0 = xb0; xa1 = xb1;
  }

#pragma unroll
  for (int t = 0; t < 6; ++t) {
    const int n = ch2 * 96 + t * 16 + lo;
    const int p = n >> 6, nn = n & 63;
#pragma unroll
    for (int r = 0; r < 4; ++r) {
      const int rgl = row0 + rg * 16 + hi * 4 + r;
      unsigned short val = f32_to_bf16(acc[t][r]);
      if (p == 0) {
        Kb[rgl * H_ + nn] = val;
      } else if (p == 1) {
        Qb[rgl * H_ + nn] = val;
      } else {
        const int b = rgl >> 11;
        const int tt = rgl & (T_ - 1);
        Vt[((b * H_ + nn) << 11) + tt] = val;
      }
    }
  }
}

// ---------------- Kernel 2: causal flash attention, split-j partials -----------------
// grid = (QT_, B, NCH_), 256 threads = 4 INDEPENDENT waves (no barriers).
// K/V read directly from global (L1/L2-resident: 16KB tile, 256KB per batch).
// V fragments preloaded to regs so their latency overlaps the softmax chain.
__global__ __launch_bounds__(256) void attn_part_kernel(
    const unsigned short* __restrict__ Qb, const unsigned short* __restrict__ Kb,
    const unsigned short* __restrict__ Vt, float* __restrict__ Op, float* __restrict__ Ml) {
  const int qt = blockIdx.x;
  const int b = blockIdx.y;
  const int ch = blockIdx.z;
  const int t0 = ch * CH_;
  if (t0 > qt) return;
  const int t1 = min(qt, t0 + CH_ - 1);

  __shared__ unsigned short p_lds[4][16 * 72];

  const int tid = threadIdx.x;
  const int wave = tid >> 6;
  const int lane = tid & 63;
  const int lo = lane & 15, hi = lane >> 4;
  const int i0 = qt * 64 + wave * 16;
  const size_t bt = (size_t)b * T_;

  ushort8 qf[2];
  qf[0] = *(const ushort8*)(Qb + (bt + i0 + lo) * H_ + hi * 8);
  qf[1] = *(const ushort8*)(Qb + (bt + i0 + lo) * H_ + 32 + hi * 8);

  const unsigned short* Krow = Kb + ((bt + lo) << 6) + hi * 8;        // + j*64 per row
  const unsigned short* Vrow = Vt + (((size_t)(b * H_ + lo)) << 11) + hi * 8;  // + d16*16*2048 + j

  f32x4 o[4];
#pragma unroll
  for (int nt = 0; nt < 4; ++nt) o[nt] = (f32x4){0.f, 0.f, 0.f, 0.f};
  float m[4] = {-1e30f, -1e30f, -1e30f, -1e30f};
  float lsum[4] = {0.f, 0.f, 0.f, 0.f};

  for (int jt = t0; jt <= t1; ++jt) {
    const int j0 = jt * 64;
    // S = Q K^T (K fragments straight from global; 1KB coalesced per load)
    f32x4 s[4];
#pragma unroll
    for (int nt = 0; nt < 4; ++nt) s[nt] = (f32x4){0.f, 0.f, 0.f, 0.f};
#pragma unroll
    for (int c = 0; c < 2; ++c)
#pragma unroll
      for (int nt = 0; nt < 4; ++nt) {
        ushort8 kf = *(const ushort8*)(Krow + ((j0 + nt * 16) << 6) + c * 32);
        s[nt] = mfma16(qf[c], kf, s[nt]);
      }
    // preload V fragments (used after softmax; latency overlaps it)
    ushort8 vf[2][4];
#pragma unroll
    for (int c = 0; c < 2; ++c)
#pragma unroll
      for (int nt = 0; nt < 4; ++nt)
        vf[c][nt] = *(const ushort8*)(Vrow + (((size_t)nt * 16) << 11) + j0 + c * 32);

    if (jt == qt) {
#pragma unroll
      for (int nt = 0; nt < 4; ++nt)
#pragma unroll
        for (int r = 0; r < 4; ++r)
          if (nt * 16 + lo > wave * 16 + hi * 4 + r) s[nt][r] = -1e30f;
    }
    float mnew[4], scl[4];
#pragma unroll
    for (int r = 0; r < 4; ++r) {
      float t = fmaxf(fmaxf(s[0][r], s[1][r]), fmaxf(s[2][r], s[3][r]));
      t = fmaxf(t, __shfl_xor(t, 1));
      t = fmaxf(t, __shfl_xor(t, 2));
      t = fmaxf(t, __shfl_xor(t, 4));
      t = fmaxf(t, __shfl_xor(t, 8));
      mnew[r] = fmaxf(m[r], t);
      scl[r] = exp2f(m[r] - mnew[r]);
      m[r] = mnew[r];
    }
    float tsum[4] = {0.f, 0.f, 0.f, 0.f};
#pragma unroll
    for (int nt = 0; nt < 4; ++nt)
#pragma unroll
      for (int r = 0; r < 4; ++r) {
        float p = exp2f(s[nt][r] - mnew[r]);
        s[nt][r] = p;
        tsum[r] += p;
      }
#pragma unroll
    for (int r = 0; r < 4; ++r) {
      float t = tsum[r];
      t += __shfl_xor(t, 1);
      t += __shfl_xor(t, 2);
      t += __shfl_xor(t, 4);
      t += __shfl_xor(t, 8);
      lsum[r] = lsum[r] * scl[r] + t;
#pragma unroll
      for (int nt = 0; nt < 4; ++nt) o[nt][r] *= scl[r];
    }
    // P (D-layout) -> per-wave LDS -> A-fragments (wave-local, no barrier)
    unsigned short* pl = p_lds[wave];
#pragma unroll
    for (int nt = 0; nt < 4; ++nt)
#pragma unroll
      for (int r = 0; r < 4; ++r)
        pl[(hi * 4 + r) * 72 + nt * 16 + lo] = f32_to_bf16(s[nt][r]);
    asm volatile("s_waitcnt lgkmcnt(0)" ::: "memory");
    __builtin_amdgcn_sched_barrier(0);
#pragma unroll
    for (int c = 0; c < 2; ++c) {
      ushort8 pf = *(const ushort8*)(pl + lo * 72 + c * 32 + hi * 8);
#pragma unroll
      for (int nt = 0; nt < 4; ++nt) o[nt] = mfma16(pf, vf[c][nt], o[nt]);
    }
  }

  const size_t pb = (size_t)(b * QT_ + qt) * NCH_ + ch;
  float* op = Op + pb * 4096;
#pragma unroll
  for (int nt = 0; nt < 4; ++nt)
#pragma unroll
    for (int r = 0; r < 4; ++r)
      op[(wave * 16 + hi * 4 + r) * 64 + nt * 16 + lo] = o[nt][r];
  if (lo == 0) {
    float* ml = Ml + pb * 128;
#pragma unroll
    for (int r = 0; r < 4; ++r) {
      ml[wave * 16 + hi * 4 + r] = m[r];
      ml[64 + wave * 16 + hi * 4 + r] = lsum[r];
    }
  }
}

// ---------------- Kernel 3: combine split-j partials ---------------------------------
__global__ __launch_bounds__(256) void attn_comb_kernel(
    const float* __restrict__ Op, const float* __restrict__ Ml, float* __restrict__ out) {
  const int qt = blockIdx.x;
  const int b = blockIdx.y;
  const int nc = (qt >> 3) + 1;
  const int row = threadIdx.x >> 2;
  const int c0 = (threadIdx.x & 3) * 16;
  const size_t pbase = (size_t)(b * QT_ + qt) * NCH_;

  float mv[NCH_], wv[NCH_];
  float m_g = -1e30f;
  for (int c = 0; c < nc; ++c) {
    mv[c] = Ml[(pbase + c) * 128 + row];
    m_g = fmaxf(m_g, mv[c]);
  }
  float l_g = 0.f;
  for (int c = 0; c < nc; ++c) {
    wv[c] = exp2f(mv[c] - m_g);
    l_g += Ml[(pbase + c) * 128 + 64 + row] * wv[c];
  }
  const float inv = 1.0f / l_g;

  f32x4 a0 = {0,0,0,0}, a1 = {0,0,0,0}, a2 = {0,0,0,0}, a3 = {0,0,0,0};
  for (int c = 0; c < nc; ++c) {
    const float* op = Op + (pbase + c) * 4096 + row * 64 + c0;
    const float wc = wv[c];
    f32x4 v0 = *(const f32x4*)(op);
    f32x4 v1 = *(const f32x4*)(op + 4);
    f32x4 v2 = *(const f32x4*)(op + 8);
    f32x4 v3 = *(const f32x4*)(op + 12);
    a0 += v0 * wc; a1 += v1 * wc; a2 += v2 * wc; a3 += v3 * wc;
  }
  float* o = out + ((size_t)b * T_ + qt * 64 + row) * 64 + c0;
  *(f32x4*)(o) = a0 * inv;
  *(f32x4*)(o + 4) = a1 * inv;
  *(f32x4*)(o + 8) = a2 * inv;
  *(f32x4*)(o + 12) = a3 * inv;
}

extern "C" void kernel_launch(void* const* d_in, const int* in_sizes, int n_in,
                              void* d_out, int out_size, void* d_ws, size_t ws_size,
                              hipStream_t stream) {
  const float* x = (const float*)d_in[0];
  const float* Wk = (const float*)d_in[1];
  const float* Wq = (const float*)d_in[2];
  const float* Wv = (const float*)d_in[3];
  float* out = (float*)d_out;

  char* ws = (char*)d_ws;
  unsigned short* Qb = (unsigned short*)(ws);                  // 2 MB   [B*T][64] bf16
  unsigned short* Kb = (unsigned short*)(ws + (2u << 20));     // 2 MB   [B*T][64] bf16
  unsigned short* Vt = (unsigned short*)(ws + (4u << 20));     // 2 MB   [B][64][T] bf16
  unsigned short* Wt = (unsigned short*)(ws + (6u << 20));     // 288 KB swizzled [24][768]x16B
  float* Op = (float*)(ws + (8u << 20));                       // 16 MB  [B][32][4][64][64] f32
  float* Ml = (float*)(ws + (24u << 20));                      // 512 KB [B][32][4][2][64] f32

  prep_w_kernel<<<dim3(72), dim3(256), 0, stream>>>(Wk, Wq, Wv, Wt);
  proj_kernel<<<dim3((B_ * T_) / 32), dim3(256), 0, stream>>>(x, Wt, Qb, Kb, Vt);
  attn_part_kernel<<<dim3(QT_, B_, NCH_), dim3(256), 0, stream>>>(Qb, Kb, Vt, Op, Ml);
  attn_comb_kernel<<<dim3(QT_, B_), dim3(256), 0, stream>>>(Op, Ml, out);
}

// Round 6
// 72.902 us; speedup vs baseline: 1.3366x; 1.3366x over previous
//
#include <hip/hip_runtime.h>

#define B_ 8
#define T_ 2048
#define C_ 768
#define H_ 64
#define QT_ (T_ / 64)   // 32 Q-tiles

typedef __bf16 bf16x8 __attribute__((ext_vector_type(8)));
typedef unsigned short ushort8 __attribute__((ext_vector_type(8)));
typedef float f32x4 __attribute__((ext_vector_type(4)));

typedef __attribute__((address_space(1))) const void g_void;
typedef __attribute__((address_space(3))) void lds_void;

static __device__ __forceinline__ unsigned short f32_to_bf16(float f) {
  unsigned int u = __float_as_uint(f);
  u += 0x7FFFu + ((u >> 16) & 1u);
  return (unsigned short)(u >> 16);
}

static __device__ __forceinline__ unsigned int cvtpk_bf16(float a, float b) {
  unsigned int r;
  asm("v_cvt_pk_bf16_f32 %0, %1, %2" : "=v"(r) : "v"(a), "v"(b));
  return r;
}

static __device__ __forceinline__ f32x4 mfma16(ushort8 a, ushort8 b, f32x4 c) {
  return __builtin_amdgcn_mfma_f32_16x16x32_bf16(
      __builtin_bit_cast(bf16x8, a), __builtin_bit_cast(bf16x8, b), c, 0, 0, 0);
}

// ---------------- Kernel 0: W -> Wt in PRE-SWIZZLED per-K-step tiled layout ----------
__global__ void prep_w_kernel(const float* __restrict__ Wk, const float* __restrict__ Wq,
                              const float* __restrict__ Wv, unsigned short* __restrict__ Wt) {
  int g = blockIdx.x * 256 + threadIdx.x;
  if (g >= 24 * 768) return;
  int ks = g / 768, s = g - ks * 768;
  int n = s >> 2, perm = s & 3;
  int k8 = perm ^ (n & 3) ^ ((n >> 2) & 3);
  int p = n >> 6, col = n & 63;
  const float* W = (p == 0) ? Wk : (p == 1) ? Wq : Wv;
  float sc = (p == 1) ? 0.125f * 1.44269504088896f : 1.0f;
  int kbase = ks * 32 + k8 * 8;
  ushort8 v;
#pragma unroll
  for (int e = 0; e < 8; ++e) v[e] = f32_to_bf16(W[(kbase + e) * 64 + col] * sc);
  *(ushort8*)(Wt + (size_t)g * 8) = v;
}

// ---------------- Kernel 1: projections as LDS-staged pipelined GEMM -----------------
__global__ __launch_bounds__(256) void proj_kernel(
    const float* __restrict__ x, const unsigned short* __restrict__ Wt,
    unsigned short* __restrict__ Qb, unsigned short* __restrict__ Kb,
    unsigned short* __restrict__ Vt) {
  __shared__ unsigned short Wl[2][6144];
  __shared__ unsigned short Xl[2][1024];
  const int tid = threadIdx.x;
  const int wave = tid >> 6, lane = tid & 63;
  const int lo = lane & 15, hi = lane >> 4;
  const int rg = wave & 1, ch2 = wave >> 1;
  const int row0 = blockIdx.x * 32;

  f32x4 acc[6];
#pragma unroll
  for (int t = 0; t < 6; ++t) acc[t] = (f32x4){0.f, 0.f, 0.f, 0.f};

  const int xr = (tid & 127) >> 2;
  const int xk8 = tid & 3;
  const int xslot = xr * 4 + (xk8 ^ (xr & 3) ^ ((xr >> 2) & 3));
  const float* xsrc = x + (size_t)(row0 + xr) * C_ + xk8 * 8;

  const int arow = rg * 16 + lo;
  const int aaddr = (arow * 4 + (hi ^ (arow & 3) ^ ((arow >> 2) & 3))) * 8;

  auto wstage = [&](int buf, int ks) {
    const unsigned short* src = Wt + (size_t)ks * 6144 + tid * 8;
#pragma unroll
    for (int is = 0; is < 3; ++is)
      __builtin_amdgcn_global_load_lds((g_void*)(src + is * 2048),
          (lds_void*)(&Wl[buf][is * 2048 + wave * 512]), 16, 0, 0);
  };

  float4 xa0 = {}, xa1 = {}, xb0 = {}, xb1 = {};

  wstage(0, 0);
  if (tid < 128) {
    xa0 = *(const float4*)(xsrc);
    xa1 = *(const float4*)(xsrc + 4);
  }

  for (int ks = 0; ks < 24; ++ks) {
    const int cur = ks & 1;
    asm volatile("s_waitcnt vmcnt(0)" ::: "memory");
    __syncthreads();
    if (ks + 1 < 24) {
      wstage(cur ^ 1, ks + 1);
      if (tid < 128) {
        xb0 = *(const float4*)(xsrc + (ks + 1) * 32);
        xb1 = *(const float4*)(xsrc + (ks + 1) * 32 + 4);
      }
    }
    if (tid < 128) {
      unsigned int dd[4];
      dd[0] = cvtpk_bf16(xa0.x, xa0.y);
      dd[1] = cvtpk_bf16(xa0.z, xa0.w);
      dd[2] = cvtpk_bf16(xa1.x, xa1.y);
      dd[3] = cvtpk_bf16(xa1.z, xa1.w);
      *(uint4*)(&Xl[cur][xslot * 8]) = *(uint4*)dd;
    }
    __syncthreads();
    ushort8 af = *(const ushort8*)(&Xl[cur][aaddr]);
#pragma unroll
    for (int t = 0; t < 6; ++t) {
      const int n = ch2 * 96 + t * 16 + lo;
      const int baddr = (n * 4 + (hi ^ (n & 3) ^ ((n >> 2) & 3))) * 8;
      ushort8 bfr = *(const ushort8*)(&Wl[cur][baddr]);
      acc[t] = mfma16(af, bfr, acc[t]);
    }
    xa0 = xb0; xa1 = xb1;
  }

#pragma unroll
  for (int t = 0; t < 6; ++t) {
    const int n = ch2 * 96 + t * 16 + lo;
    const int p = n >> 6, nn = n & 63;
#pragma unroll
    for (int r = 0; r < 4; ++r) {
      const int rgl = row0 + rg * 16 + hi * 4 + r;
      unsigned short val = f32_to_bf16(acc[t][r]);
      if (p == 0) {
        Kb[rgl * H_ + nn] = val;
      } else if (p == 1) {
        Qb[rgl * H_ + nn] = val;
      } else {
        const int b = rgl >> 11;
        const int tt = rgl & (T_ - 1);
        Vt[((b * H_ + nn) << 11) + tt] = val;
      }
    }
  }
}

// ---------------- Kernel 2: causal flash attention, split-j partials -----------------
// grid = (QT_, B, nch); block (qt,b,ch) processes j-tiles [ch*chsz, min(qt, +chsz-1)].
// Round-4 staged structure (best measured): K/V double-buffered LDS via
// global_load_lds, XOR-swizzled; emits un-normalized O + per-row (m,l) log2 units.
__global__ __launch_bounds__(256) void attn_part_kernel(
    const unsigned short* __restrict__ Qb, const unsigned short* __restrict__ Kb,
    const unsigned short* __restrict__ Vt, float* __restrict__ Op, float* __restrict__ Ml,
    int chsz, int nch) {
  const int qt = blockIdx.x;
  const int b = blockIdx.y;
  const int ch = blockIdx.z;
  const int t0 = ch * chsz;
  if (t0 > qt) return;
  const int t1 = min(qt, t0 + chsz - 1);

  __shared__ unsigned short Kl[2][64 * 64];
  __shared__ unsigned short Vl[2][64 * 64];
  __shared__ unsigned short p_lds[4][16 * 72];

  const int tid = threadIdx.x;
  const int wave = tid >> 6;
  const int lane = tid & 63;
  const int lo = lane & 15, hi = lane >> 4;
  const int i0 = qt * 64 + wave * 16;
  const size_t bt = (size_t)b * T_;

  const int srow = tid >> 3;
  const int sslot = (tid & 7) ^ (srow & 7);
  const int ldsoff = (tid >> 6) * 512;

  ushort8 qf[2];
  qf[0] = *(const ushort8*)(Qb + (bt + i0 + lo) * H_ + hi * 8);
  qf[1] = *(const ushort8*)(Qb + (bt + i0 + lo) * H_ + 32 + hi * 8);

  f32x4 o[4];
#pragma unroll
  for (int nt = 0; nt < 4; ++nt) o[nt] = (f32x4){0.f, 0.f, 0.f, 0.f};
  float m[4] = {-1e30f, -1e30f, -1e30f, -1e30f};
  float lsum[4] = {0.f, 0.f, 0.f, 0.f};

  auto stage = [&](int buf, int jt) {
    const int j0 = jt * 64;
#pragma unroll
    for (int is = 0; is < 2; ++is) {
      const int j = is * 32 + srow;
      const unsigned short* gK = Kb + ((bt + j0 + j) << 6) + (sslot << 3);
      __builtin_amdgcn_global_load_lds((g_void*)gK,
          (lds_void*)(&Kl[buf][is * 2048 + ldsoff]), 16, 0, 0);
    }
#pragma unroll
    for (int is = 0; is < 2; ++is) {
      const int d = is * 32 + srow;
      const unsigned short* gV = Vt + (((size_t)(b * H_ + d)) << 11) + j0 + (sslot << 3);
      __builtin_amdgcn_global_load_lds((g_void*)gV,
          (lds_void*)(&Vl[buf][is * 2048 + ldsoff]), 16, 0, 0);
    }
  };

  stage(0, t0);

  for (int jt = t0; jt <= t1; ++jt) {
    const int cur = (jt - t0) & 1;
    asm volatile("s_waitcnt vmcnt(0)" ::: "memory");
    __syncthreads();
    if (jt < t1) stage(cur ^ 1, jt + 1);

    f32x4 s[4];
#pragma unroll
    for (int nt = 0; nt < 4; ++nt) s[nt] = (f32x4){0.f, 0.f, 0.f, 0.f};
#pragma unroll
    for (int c = 0; c < 2; ++c) {
#pragma unroll
      for (int nt = 0; nt < 4; ++nt) {
        const int j = nt * 16 + lo;
        ushort8 kf = *(const ushort8*)(&Kl[cur][(j << 6) + ((((c << 2) + hi) ^ (lo & 7)) << 3)]);
        s[nt] = mfma16(qf[c], kf, s[nt]);
      }
    }
    if (jt == qt) {
#pragma unroll
      for (int nt = 0; nt < 4; ++nt)
#pragma unroll
        for (int r = 0; r < 4; ++r)
          if (nt * 16 + lo > wave * 16 + hi * 4 + r) s[nt][r] = -1e30f;
    }
    float mnew[4], scl[4];
#pragma unroll
    for (int r = 0; r < 4; ++r) {
      float t = fmaxf(fmaxf(s[0][r], s[1][r]), fmaxf(s[2][r], s[3][r]));
      t = fmaxf(t, __shfl_xor(t, 1));
      t = fmaxf(t, __shfl_xor(t, 2));
      t = fmaxf(t, __shfl_xor(t, 4));
      t = fmaxf(t, __shfl_xor(t, 8));
      mnew[r] = fmaxf(m[r], t);
      scl[r] = exp2f(m[r] - mnew[r]);
      m[r] = mnew[r];
    }
    float tsum[4] = {0.f, 0.f, 0.f, 0.f};
#pragma unroll
    for (int nt = 0; nt < 4; ++nt)
#pragma unroll
      for (int r = 0; r < 4; ++r) {
        float p = exp2f(s[nt][r] - mnew[r]);
        s[nt][r] = p;
        tsum[r] += p;
      }
#pragma unroll
    for (int r = 0; r < 4; ++r) {
      float t = tsum[r];
      t += __shfl_xor(t, 1);
      t += __shfl_xor(t, 2);
      t += __shfl_xor(t, 4);
      t += __shfl_xor(t, 8);
      lsum[r] = lsum[r] * scl[r] + t;
#pragma unroll
      for (int nt = 0; nt < 4; ++nt) o[nt][r] *= scl[r];
    }
    unsigned short* pl = p_lds[wave];
#pragma unroll
    for (int nt = 0; nt < 4; ++nt)
#pragma unroll
      for (int r = 0; r < 4; ++r)
        pl[(hi * 4 + r) * 72 + nt * 16 + lo] = f32_to_bf16(s[nt][r]);
    asm volatile("s_waitcnt lgkmcnt(0)" ::: "memory");
    __builtin_amdgcn_sched_barrier(0);
#pragma unroll
    for (int c = 0; c < 2; ++c) {
      ushort8 pf = *(const ushort8*)(pl + lo * 72 + c * 32 + hi * 8);
#pragma unroll
      for (int nt = 0; nt < 4; ++nt) {
        const int d = nt * 16 + lo;
        ushort8 vf = *(const ushort8*)(&Vl[cur][(d << 6) + ((((c << 2) + hi) ^ (lo & 7)) << 3)]);
        o[nt] = mfma16(pf, vf, o[nt]);
      }
    }
  }

  const size_t pb = (size_t)(b * QT_ + qt) * nch + ch;
  float* op = Op + pb * 4096;
#pragma unroll
  for (int nt = 0; nt < 4; ++nt)
#pragma unroll
    for (int r = 0; r < 4; ++r)
      op[(wave * 16 + hi * 4 + r) * 64 + nt * 16 + lo] = o[nt][r];
  if (lo == 0) {
    float* ml = Ml + pb * 128;
#pragma unroll
    for (int r = 0; r < 4; ++r) {
      ml[wave * 16 + hi * 4 + r] = m[r];
      ml[64 + wave * 16 + hi * 4 + r] = lsum[r];
    }
  }
}

// ---------------- Kernel 3: combine split-j partials ---------------------------------
// No local arrays (avoid scratch): 3 cheap re-reads of Ml (L2-hot).
__global__ __launch_bounds__(256) void attn_comb_kernel(
    const float* __restrict__ Op, const float* __restrict__ Ml, float* __restrict__ out,
    int chsz, int nch) {
  const int qt = blockIdx.x;
  const int b = blockIdx.y;
  const int nc = qt / chsz + 1;
  const int row = threadIdx.x >> 2;
  const int c0 = (threadIdx.x & 3) * 16;
  const size_t pbase = (size_t)(b * QT_ + qt) * nch;

  float m_g = -1e30f;
  for (int c = 0; c < nc; ++c) m_g = fmaxf(m_g, Ml[(pbase + c) * 128 + row]);
  float l_g = 0.f;
  for (int c = 0; c < nc; ++c)
    l_g += Ml[(pbase + c) * 128 + 64 + row] * exp2f(Ml[(pbase + c) * 128 + row] - m_g);
  const float inv = 1.0f / l_g;

  f32x4 a0 = {0,0,0,0}, a1 = {0,0,0,0}, a2 = {0,0,0,0}, a3 = {0,0,0,0};
  for (int c = 0; c < nc; ++c) {
    const float wc = exp2f(Ml[(pbase + c) * 128 + row] - m_g);
    const float* op = Op + (pbase + c) * 4096 + row * 64 + c0;
    a0 += *(const f32x4*)(op) * wc;
    a1 += *(const f32x4*)(op + 4) * wc;
    a2 += *(const f32x4*)(op + 8) * wc;
    a3 += *(const f32x4*)(op + 12) * wc;
  }
  float* o = out + ((size_t)b * T_ + qt * 64 + row) * 64 + c0;
  *(f32x4*)(o) = a0 * inv;
  *(f32x4*)(o + 4) = a1 * inv;
  *(f32x4*)(o + 8) = a2 * inv;
  *(f32x4*)(o + 12) = a3 * inv;
}

extern "C" void kernel_launch(void* const* d_in, const int* in_sizes, int n_in,
                              void* d_out, int out_size, void* d_ws, size_t ws_size,
                              hipStream_t stream) {
  const float* x = (const float*)d_in[0];
  const float* Wk = (const float*)d_in[1];
  const float* Wq = (const float*)d_in[2];
  const float* Wv = (const float*)d_in[3];
  float* out = (float*)d_out;

  char* ws = (char*)d_ws;
  unsigned short* Qb = (unsigned short*)(ws);                  // 2 MB   [B*T][64] bf16
  unsigned short* Kb = (unsigned short*)(ws + (2u << 20));     // 2 MB   [B*T][64] bf16
  unsigned short* Vt = (unsigned short*)(ws + (4u << 20));     // 2 MB   [B][64][T] bf16
  unsigned short* Wt = (unsigned short*)(ws + (6u << 20));     // 288 KB swizzled
  float* Op = (float*)(ws + (8u << 20));                       // nch*4 MB partial O
  // chunk size: prefer 4 (8 chunks, 1152 blocks) if workspace allows, else 8.
  const size_t need8 = (8u << 20) + (size_t)8 * 4096 * B_ * QT_ * 4 + (size_t)8 * 128 * B_ * QT_ * 4;
  const int chsz = (ws_size >= need8) ? 4 : 8;
  const int nch = QT_ / chsz;
  float* Ml = (float*)(ws + (8u << 20) + (size_t)nch * 4096 * B_ * QT_ * 4);

  prep_w_kernel<<<dim3(72), dim3(256), 0, stream>>>(Wk, Wq, Wv, Wt);
  proj_kernel<<<dim3((B_ * T_) / 32), dim3(256), 0, stream>>>(x, Wt, Qb, Kb, Vt);
  attn_part_kernel<<<dim3(QT_, B_, nch), dim3(256), 0, stream>>>(Qb, Kb, Vt, Op, Ml, chsz, nch);
  attn_comb_kernel<<<dim3(QT_, B_), dim3(256), 0, stream>>>(Op, Ml, out, chsz, nch);
}

// Round 7
// 65.350 us; speedup vs baseline: 1.4910x; 1.1156x over previous
//
#include <hip/hip_runtime.h>

#define B_ 8
#define T_ 2048
#define C_ 768
#define H_ 64
#define QT_ (T_ / 64)   // 32 Q-tiles

typedef __bf16 bf16x8 __attribute__((ext_vector_type(8)));
typedef unsigned short ushort8 __attribute__((ext_vector_type(8)));
typedef float f32x4 __attribute__((ext_vector_type(4)));
typedef float f32x16 __attribute__((ext_vector_type(16)));

typedef __attribute__((address_space(1))) const void g_void;
typedef __attribute__((address_space(3))) void lds_void;

static __device__ __forceinline__ unsigned short f32_to_bf16(float f) {
  unsigned int u = __float_as_uint(f);
  u += 0x7FFFu + ((u >> 16) & 1u);
  return (unsigned short)(u >> 16);
}

static __device__ __forceinline__ unsigned int cvtpk_bf16(float a, float b) {
  unsigned int r;
  asm("v_cvt_pk_bf16_f32 %0, %1, %2" : "=v"(r) : "v"(a), "v"(b));
  return r;
}

static __device__ __forceinline__ f32x4 mfma16(ushort8 a, ushort8 b, f32x4 c) {
  return __builtin_amdgcn_mfma_f32_16x16x32_bf16(
      __builtin_bit_cast(bf16x8, a), __builtin_bit_cast(bf16x8, b), c, 0, 0, 0);
}

static __device__ __forceinline__ f32x16 mfma32(ushort8 a, ushort8 b, f32x16 c) {
  return __builtin_amdgcn_mfma_f32_32x32x16_bf16(
      __builtin_bit_cast(bf16x8, a), __builtin_bit_cast(bf16x8, b), c, 0, 0, 0);
}

// Pack 8 fp32 P-values (regs p[BASE..BASE+7], S^T layout) into one A/B-fragment
// for the swapped PV mfma: word w holds k-pair (2w,2w+1); lane-half redistribution
// via v_permlane32_swap (T12). Verified mapping: reg r of S^T holds
// j' = (r&3)+8*(r>>2)+4*(lane>>5); fragment needs k=(lane>>5)*8+e.
template <int BASE>
static __device__ __forceinline__ ushort8 packA(const f32x16& p) {
  unsigned int a1 = cvtpk_bf16(p[BASE + 0], p[BASE + 1]);
  unsigned int a2 = cvtpk_bf16(p[BASE + 2], p[BASE + 3]);
  unsigned int a3 = cvtpk_bf16(p[BASE + 4], p[BASE + 5]);
  unsigned int a4 = cvtpk_bf16(p[BASE + 6], p[BASE + 7]);
  asm("v_permlane32_swap_b32 %0, %1" : "+v"(a1), "+v"(a3));
  asm("v_permlane32_swap_b32 %0, %1" : "+v"(a2), "+v"(a4));
  uint4 w = {a1, a2, a3, a4};
  return __builtin_bit_cast(ushort8, w);
}

// ---------------- Kernel 0: W -> Wt in PRE-SWIZZLED per-K-step tiled layout ----------
__global__ void prep_w_kernel(const float* __restrict__ Wk, const float* __restrict__ Wq,
                              const float* __restrict__ Wv, unsigned short* __restrict__ Wt) {
  int g = blockIdx.x * 256 + threadIdx.x;
  if (g >= 24 * 768) return;
  int ks = g / 768, s = g - ks * 768;
  int n = s >> 2, perm = s & 3;
  int k8 = perm ^ (n & 3) ^ ((n >> 2) & 3);
  int p = n >> 6, col = n & 63;
  const float* W = (p == 0) ? Wk : (p == 1) ? Wq : Wv;
  float sc = (p == 1) ? 0.125f * 1.44269504088896f : 1.0f;
  int kbase = ks * 32 + k8 * 8;
  ushort8 v;
#pragma unroll
  for (int e = 0; e < 8; ++e) v[e] = f32_to_bf16(W[(kbase + e) * 64 + col] * sc);
  *(ushort8*)(Wt + (size_t)g * 8) = v;
}

// ---------------- Kernel 1: projections as LDS-staged pipelined GEMM -----------------
__global__ __launch_bounds__(256) void proj_kernel(
    const float* __restrict__ x, const unsigned short* __restrict__ Wt,
    unsigned short* __restrict__ Qb, unsigned short* __restrict__ Kb,
    unsigned short* __restrict__ Vt) {
  __shared__ unsigned short Wl[2][6144];
  __shared__ unsigned short Xl[2][1024];
  const int tid = threadIdx.x;
  const int wave = tid >> 6, lane = tid & 63;
  const int lo = lane & 15, hi = lane >> 4;
  const int rg = wave & 1, ch2 = wave >> 1;
  const int row0 = blockIdx.x * 32;

  f32x4 acc[6];
#pragma unroll
  for (int t = 0; t < 6; ++t) acc[t] = (f32x4){0.f, 0.f, 0.f, 0.f};

  const int xr = (tid & 127) >> 2;
  const int xk8 = tid & 3;
  const int xslot = xr * 4 + (xk8 ^ (xr & 3) ^ ((xr >> 2) & 3));
  const float* xsrc = x + (size_t)(row0 + xr) * C_ + xk8 * 8;

  const int arow = rg * 16 + lo;
  const int aaddr = (arow * 4 + (hi ^ (arow & 3) ^ ((arow >> 2) & 3))) * 8;

  auto wstage = [&](int buf, int ks) {
    const unsigned short* src = Wt + (size_t)ks * 6144 + tid * 8;
#pragma unroll
    for (int is = 0; is < 3; ++is)
      __builtin_amdgcn_global_load_lds((g_void*)(src + is * 2048),
          (lds_void*)(&Wl[buf][is * 2048 + wave * 512]), 16, 0, 0);
  };

  float4 xa0 = {}, xa1 = {}, xb0 = {}, xb1 = {};

  wstage(0, 0);
  if (tid < 128) {
    xa0 = *(const float4*)(xsrc);
    xa1 = *(const float4*)(xsrc + 4);
  }

  for (int ks = 0; ks < 24; ++ks) {
    const int cur = ks & 1;
    asm volatile("s_waitcnt vmcnt(0)" ::: "memory");
    __syncthreads();
    if (ks + 1 < 24) {
      wstage(cur ^ 1, ks + 1);
      if (tid < 128) {
        xb0 = *(const float4*)(xsrc + (ks + 1) * 32);
        xb1 = *(const float4*)(xsrc + (ks + 1) * 32 + 4);
      }
    }
    if (tid < 128) {
      unsigned int dd[4];
      dd[0] = cvtpk_bf16(xa0.x, xa0.y);
      dd[1] = cvtpk_bf16(xa0.z, xa0.w);
      dd[2] = cvtpk_bf16(xa1.x, xa1.y);
      dd[3] = cvtpk_bf16(xa1.z, xa1.w);
      *(uint4*)(&Xl[cur][xslot * 8]) = *(uint4*)dd;
    }
    __syncthreads();
    ushort8 af = *(const ushort8*)(&Xl[cur][aaddr]);
#pragma unroll
    for (int t = 0; t < 6; ++t) {
      const int n = ch2 * 96 + t * 16 + lo;
      const int baddr = (n * 4 + (hi ^ (n & 3) ^ ((n >> 2) & 3))) * 8;
      ushort8 bfr = *(const ushort8*)(&Wl[cur][baddr]);
      acc[t] = mfma16(af, bfr, acc[t]);
    }
    xa0 = xb0; xa1 = xb1;
  }

#pragma unroll
  for (int t = 0; t < 6; ++t) {
    const int n = ch2 * 96 + t * 16 + lo;
    const int p = n >> 6, nn = n & 63;
#pragma unroll
    for (int r = 0; r < 4; ++r) {
      const int rgl = row0 + rg * 16 + hi * 4 + r;
      unsigned short val = f32_to_bf16(acc[t][r]);
      if (p == 0) {
        Kb[rgl * H_ + nn] = val;
      } else if (p == 1) {
        Qb[rgl * H_ + nn] = val;
      } else {
        const int b = rgl >> 11;
        const int tt = rgl & (T_ - 1);
        Vt[((b * H_ + nn) << 11) + tt] = val;
      }
    }
  }
}

// ---------------- Kernel 2: swapped-operand 32x32 flash attention, split-j -----------
// grid = (QT_, B, nch), 128 threads = 2 waves; wave w owns q-rows [qt*64+w*32, +32).
// S^T = mfma32(K, Q): lane holds full P-row for i = i0w + (lane&31); softmax is
// reg-local + one shfl_xor(32). P packed to bf16 fragments in-register via
// cvt_pk + permlane32_swap. PV swapped too: o^T = mfma32(V, P) => rescale lane-local.
__global__ __launch_bounds__(128) void attn_part_kernel(
    const unsigned short* __restrict__ Qb, const unsigned short* __restrict__ Kb,
    const unsigned short* __restrict__ Vt, float* __restrict__ Op, float* __restrict__ Ml,
    int chsz, int nch) {
  const int qt = blockIdx.x;
  const int b = blockIdx.y;
  const int ch = blockIdx.z;
  const int t0 = ch * chsz;
  if (t0 > qt) return;
  const int t1 = min(qt, t0 + chsz - 1);

  __shared__ __align__(16) unsigned short Kl[2][4096];  // [j][d8^swz] 8KB each
  __shared__ __align__(16) unsigned short Vl[2][4096];  // [d][j8^swz]

  const int tid = threadIdx.x;
  const int wave = tid >> 6;
  const int lane = tid & 63;
  const int il = lane & 31;     // i (and D-col) within wave
  const int h = lane >> 5;      // lane half
  const int i0w = qt * 64 + wave * 32;
  const size_t bt = (size_t)b * T_;

  // staging mapping: 128 threads x 16B, 4 issues per 8KB tile
  const int srow = tid >> 3;                 // 0..15
  const int sslot = (tid & 7) ^ (srow & 7);  // pre-swizzled source slot

  // Q fragments (B-operand: col=i=il, k = dc*16 + h*8 + e), prescaled
  ushort8 qf[4];
#pragma unroll
  for (int dc = 0; dc < 4; ++dc)
    qf[dc] = *(const ushort8*)(Qb + (bt + i0w + il) * 64 + dc * 16 + h * 8);

  f32x16 o0 = {}, o1 = {};      // o^T d-blocks [0,32) and [32,64): col=i, rows=d
  float m = -1e30f, lsum = 0.f; // per-lane row stats for i = i0w + il

  auto stage = [&](int buf, int jt) {
    const int j0 = jt * 64;
#pragma unroll
    for (int is = 0; is < 4; ++is) {
      const unsigned short* gK = Kb + ((bt + j0 + is * 16 + srow) << 6) + (sslot << 3);
      __builtin_amdgcn_global_load_lds((g_void*)gK,
          (lds_void*)(&Kl[buf][is * 1024 + wave * 512]), 16, 0, 0);
    }
#pragma unroll
    for (int is = 0; is < 4; ++is) {
      const unsigned short* gV = Vt + (((size_t)(b * H_ + is * 16 + srow)) << 11) + j0 + (sslot << 3);
      __builtin_amdgcn_global_load_lds((g_void*)gV,
          (lds_void*)(&Vl[buf][is * 1024 + wave * 512]), 16, 0, 0);
    }
  };

  stage(0, t0);

  for (int jt = t0; jt <= t1; ++jt) {
    const int cur = (jt - t0) & 1;
    asm volatile("s_waitcnt vmcnt(0)" ::: "memory");
    __syncthreads();
    if (jt < t1) stage(cur ^ 1, jt + 1);
    const int j0 = jt * 64;

    // S^T = K Q^T : A = K rows (j), B = Q rows (i); acc over 4 d-chunks
    f32x16 s0 = {}, s1 = {};
    const unsigned short* KL = Kl[cur];
#pragma unroll
    for (int dc = 0; dc < 4; ++dc) {
      const int swz = ((dc * 2 + h) ^ (il & 7)) << 3;
      ushort8 k0 = *(const ushort8*)(&KL[(il << 6) + swz]);
      ushort8 k1 = *(const ushort8*)(&KL[((32 + il) << 6) + swz]);
      s0 = mfma32(k0, qf[dc], s0);
      s1 = mfma32(k1, qf[dc], s1);
    }

    // causal mask on diagonal tile: D row = j' = (r&3)+8*(r>>2)+4*h, col = i
    if (jt == qt) {
      const int ig = i0w + il;
#pragma unroll
      for (int r = 0; r < 16; ++r) {
        const int jl = j0 + (r & 3) + 8 * (r >> 2) + 4 * h;
        if (jl > ig) s0[r] = -1e30f;
        if (jl + 32 > ig) s1[r] = -1e30f;
      }
    }

    // online softmax: reg-local over 32 values + one cross-half combine
    float tm = s0[0];
#pragma unroll
    for (int r = 1; r < 16; ++r) tm = fmaxf(tm, s0[r]);
#pragma unroll
    for (int r = 0; r < 16; ++r) tm = fmaxf(tm, s1[r]);
    tm = fmaxf(tm, __shfl_xor(tm, 32));
    const float mnew = fmaxf(m, tm);
    const float scl = exp2f(m - mnew);
    m = mnew;
    float ts = 0.f;
#pragma unroll
    for (int r = 0; r < 16; ++r) { s0[r] = exp2f(s0[r] - mnew); ts += s0[r]; }
#pragma unroll
    for (int r = 0; r < 16; ++r) { s1[r] = exp2f(s1[r] - mnew); ts += s1[r]; }
    ts += __shfl_xor(ts, 32);
    lsum = lsum * scl + ts;
    o0 *= scl;
    o1 *= scl;

    // O^T += V P^T : A = V rows (d), B = packed P (col=i, k=j); 4 j-chunks of 16
    const unsigned short* VL = Vl[cur];
#pragma unroll
    for (int c = 0; c < 4; ++c) {
      ushort8 pa = (c == 0) ? packA<0>(s0) : (c == 1) ? packA<8>(s0)
                 : (c == 2) ? packA<0>(s1) : packA<8>(s1);
      const int swz = ((c * 2 + h) ^ (il & 7)) << 3;
      ushort8 v0 = *(const ushort8*)(&VL[(il << 6) + swz]);
      ushort8 v1 = *(const ushort8*)(&VL[((32 + il) << 6) + swz]);
      o0 = mfma32(v0, pa, o0);
      o1 = mfma32(v1, pa, o1);
    }
  }

  // store partials: o^T lane holds col i = wave*32+il, rows d per reg pattern
  const size_t pb = (size_t)(b * QT_ + qt) * nch + ch;
  float* op = Op + pb * 4096 + (size_t)(wave * 32 + il) * 64;
#pragma unroll
  for (int r = 0; r < 16; ++r) {
    const int dl = (r & 3) + 8 * (r >> 2) + 4 * h;
    op[dl] = o0[r];
    op[32 + dl] = o1[r];
  }
  if (h == 0) {
    float* ml = Ml + pb * 128;
    ml[wave * 32 + il] = m;
    ml[64 + wave * 32 + il] = lsum;
  }
}

// ---------------- Kernel 3: combine split-j partials ---------------------------------
__global__ __launch_bounds__(256) void attn_comb_kernel(
    const float* __restrict__ Op, const float* __restrict__ Ml, float* __restrict__ out,
    int chsz, int nch) {
  const int qt = blockIdx.x;
  const int b = blockIdx.y;
  const int nc = qt / chsz + 1;
  const int row = threadIdx.x >> 2;
  const int c0 = (threadIdx.x & 3) * 16;
  const size_t pbase = (size_t)(b * QT_ + qt) * nch;

  float m_g = -1e30f;
  for (int c = 0; c < nc; ++c) m_g = fmaxf(m_g, Ml[(pbase + c) * 128 + row]);
  float l_g = 0.f;
  for (int c = 0; c < nc; ++c)
    l_g += Ml[(pbase + c) * 128 + 64 + row] * exp2f(Ml[(pbase + c) * 128 + row] - m_g);
  const float inv = 1.0f / l_g;

  f32x4 a0 = {0,0,0,0}, a1 = {0,0,0,0}, a2 = {0,0,0,0}, a3 = {0,0,0,0};
  for (int c = 0; c < nc; ++c) {
    const float wc = exp2f(Ml[(pbase + c) * 128 + row] - m_g);
    const float* op = Op + (pbase + c) * 4096 + row * 64 + c0;
    a0 += *(const f32x4*)(op) * wc;
    a1 += *(const f32x4*)(op + 4) * wc;
    a2 += *(const f32x4*)(op + 8) * wc;
    a3 += *(const f32x4*)(op + 12) * wc;
  }
  float* o = out + ((size_t)b * T_ + qt * 64 + row) * 64 + c0;
  *(f32x4*)(o) = a0 * inv;
  *(f32x4*)(o + 4) = a1 * inv;
  *(f32x4*)(o + 8) = a2 * inv;
  *(f32x4*)(o + 12) = a3 * inv;
}

extern "C" void kernel_launch(void* const* d_in, const int* in_sizes, int n_in,
                              void* d_out, int out_size, void* d_ws, size_t ws_size,
                              hipStream_t stream) {
  const float* x = (const float*)d_in[0];
  const float* Wk = (const float*)d_in[1];
  const float* Wq = (const float*)d_in[2];
  const float* Wv = (const float*)d_in[3];
  float* out = (float*)d_out;

  char* ws = (char*)d_ws;
  unsigned short* Qb = (unsigned short*)(ws);                  // 2 MB   [B*T][64] bf16
  unsigned short* Kb = (unsigned short*)(ws + (2u << 20));     // 2 MB   [B*T][64] bf16
  unsigned short* Vt = (unsigned short*)(ws + (4u << 20));     // 2 MB   [B][64][T] bf16
  unsigned short* Wt = (unsigned short*)(ws + (6u << 20));     // 288 KB swizzled
  float* Op = (float*)(ws + (8u << 20));                       // nch*4 MB partial O
  const size_t need8 = (8u << 20) + (size_t)8 * 4096 * B_ * QT_ * 4 + (size_t)8 * 128 * B_ * QT_ * 4;
  const int chsz = (ws_size >= need8) ? 4 : 8;
  const int nch = QT_ / chsz;
  float* Ml = (float*)(ws + (8u << 20) + (size_t)nch * 4096 * B_ * QT_ * 4);

  prep_w_kernel<<<dim3(72), dim3(256), 0, stream>>>(Wk, Wq, Wv, Wt);
  proj_kernel<<<dim3((B_ * T_) / 32), dim3(256), 0, stream>>>(x, Wt, Qb, Kb, Vt);
  attn_part_kernel<<<dim3(QT_, B_, nch), dim3(128), 0, stream>>>(Qb, Kb, Vt, Op, Ml, chsz, nch);
  attn_comb_kernel<<<dim3(QT_, B_), dim3(256), 0, stream>>>(Op, Ml, out, chsz, nch);
}